// Round 3
// baseline (1404.610 us; speedup 1.0000x reference)
//
#include <hip/hip_runtime.h>

// GIN: 2x GINConv(eps=0, MLP 2-layer) + ReLU, then Linear(128->1).
// N=50000 nodes, E=800000 edges, IN=64, HID=128.
//
// Round 3: fix GEMM register spills (was VGPR=256 + 10x scratch write
// amplification). KT=32, __launch_bounds__(256,4) caps VGPR at 128,
// outer K loop not unrolled, HAS_ADD templated.

#define N_NODES 50000
#define IN_CH 64
#define HID 128

// ---------------- edge dtype detection (int64 vs int32) ----------------
__global__ void detect64_kernel(const int* __restrict__ ei32, int* __restrict__ flag) {
    int t = threadIdx.x;  // 256 threads
    int v = ei32[2 * t + 1];
    unsigned long long b = __ballot(v != 0);
    __shared__ unsigned long long r[4];
    if ((t & 63) == 0) r[t >> 6] = b;
    __syncthreads();
    if (t == 0) flag[0] = ((r[0] | r[1] | r[2] | r[3]) == 0ULL) ? 1 : 0;
}

__device__ __forceinline__ int load_idx(const void* ei, int is64, int pos) {
    if (is64) return (int)((const long long*)ei)[pos];
    return ((const int*)ei)[pos];
}

// ---------------- CSR build ----------------
__global__ __launch_bounds__(256) void hist_kernel(
    const void* __restrict__ ei, const int* __restrict__ is64,
    int* __restrict__ deg, int E)
{
    int e = blockIdx.x * blockDim.x + threadIdx.x;
    if (e >= E) return;
    int d = load_idx(ei, *is64, E + e);
    atomicAdd(&deg[d], 1);
}

__device__ __forceinline__ int wave_incl_scan(int v, int lane) {
    #pragma unroll
    for (int off = 1; off < 64; off <<= 1) {
        int u = __shfl_up(v, off);
        if (lane >= off) v += u;
    }
    return v;
}

__global__ __launch_bounds__(256) void scan1_kernel(
    const int* __restrict__ deg, int* __restrict__ incl,
    int* __restrict__ bsum, int N)
{
    int i = blockIdx.x * 256 + threadIdx.x;
    int lane = threadIdx.x & 63;
    int w = threadIdx.x >> 6;
    int v = (i < N) ? deg[i] : 0;
    int s = wave_incl_scan(v, lane);
    __shared__ int wsum[4];
    if (lane == 63) wsum[w] = s;
    __syncthreads();
    int off = 0;
    #pragma unroll
    for (int k = 0; k < 4; k++) if (k < w) off += wsum[k];
    s += off;
    if (i < N) incl[i] = s;
    if (threadIdx.x == 255) bsum[blockIdx.x] = s;
}

__global__ __launch_bounds__(256) void scan2_kernel(
    const int* __restrict__ bsum, int* __restrict__ bsx, int nb)
{
    int t = threadIdx.x;
    int lane = t & 63;
    int w = t >> 6;
    int v = (t < nb) ? bsum[t] : 0;
    int s = wave_incl_scan(v, lane);
    __shared__ int wsum[4];
    if (lane == 63) wsum[w] = s;
    __syncthreads();
    int off = 0;
    #pragma unroll
    for (int k = 0; k < 4; k++) if (k < w) off += wsum[k];
    s += off;
    if (t < nb) bsx[t] = s - v;   // exclusive
}

__global__ __launch_bounds__(256) void scan3_kernel(
    int* __restrict__ deg_cursor, int* __restrict__ incl_rowptr,
    const int* __restrict__ bsx, int N)
{
    int i = blockIdx.x * 256 + threadIdx.x;
    if (i >= N) return;
    int incl = incl_rowptr[i] + bsx[blockIdx.x];
    int d = deg_cursor[i];
    int excl = incl - d;
    incl_rowptr[i] = excl;        // row_ptr[i]
    deg_cursor[i] = excl;         // cursor[i]
    if (i == N - 1) incl_rowptr[N] = incl;
}

__global__ __launch_bounds__(256) void fill_kernel(
    const void* __restrict__ ei, const int* __restrict__ is64,
    int* __restrict__ cursor, int* __restrict__ col, int E)
{
    int e = blockIdx.x * blockDim.x + threadIdx.x;
    if (e >= E) return;
    int i64 = *is64;
    int s = load_idx(ei, i64, e);
    int d = load_idx(ei, i64, E + e);
    int pos = atomicAdd(&cursor[d], 1);
    col[pos] = s;
}

// ---------------- gather aggregation: agg[n] = sum_{j in nbrs(n)} h[j] ----------------
template<int C>
__global__ __launch_bounds__(256) void gather_agg_kernel(
    const float* __restrict__ h, const int* __restrict__ rp,
    const int* __restrict__ col, float* __restrict__ agg, int N)
{
    int wid = (blockIdx.x * blockDim.x + threadIdx.x) >> 6;
    int lane = threadIdx.x & 63;
    if (wid >= N) return;
    int b = rp[wid], e2 = rp[wid + 1];
    float2 acc = make_float2(0.f, 0.f);
    for (int base = b; base < e2; base += 64) {
        int cnt = e2 - base; if (cnt > 64) cnt = 64;
        int myc = (base + lane < e2) ? col[base + lane] : 0;
        for (int j = 0; j < cnt; j++) {
            int s = __shfl(myc, j);
            if (C == 128) {
                float2 v = *(const float2*)(h + (size_t)s * C + lane * 2);
                acc.x += v.x; acc.y += v.y;
            } else {
                acc.x += h[(size_t)s * C + lane];
            }
        }
    }
    if (C == 128) {
        *(float2*)(agg + (size_t)wid * C + lane * 2) = acc;
    } else {
        agg[(size_t)wid * C + lane] = acc.x;
    }
}

// ---------------- fp32 GEMM: out[N][128] = act((A (+Aadd)) @ W + b) ----------------
// 64 rows/block, 256 threads, 8x4 register tile. KT=32.
// LDS: Ws 32x128 (16KB) + As 64x36 (9.2KB) = ~25KB.
// __launch_bounds__(256,4): VGPR cap 128 -> no spills (was 256 + scratch).
template<int K, bool RELU, bool HAS_ADD>
__global__ __launch_bounds__(256, 4) void gemm_mlp_kernel(
    const float* __restrict__ A, const float* __restrict__ Aadd,
    const float* __restrict__ W, const float* __restrict__ bias,
    float* __restrict__ out, int N)
{
    constexpr int KT = 32;
    constexpr int NT = 64;
    __shared__ float Ws[KT][128];
    __shared__ float As[NT][KT + 4];

    const int t  = threadIdx.x;
    const int tx = t & 31;                 // col group: cols tx*4 .. tx*4+3
    const int ty = t >> 5;                 // row group: rows ty*8 .. ty*8+7
    const int n0 = blockIdx.x * NT;

    float acc[8][4];
    #pragma unroll
    for (int i = 0; i < 8; i++)
        #pragma unroll
        for (int j = 0; j < 4; j++) acc[i][j] = 0.f;

    #pragma unroll 1
    for (int k0 = 0; k0 < K; k0 += KT) {
        // stage W tile: KT x 128 (32 rows x 32 float4 = 1024 float4, 4/thread)
        {
            int lr = t & 31;               // float4 index in row
            int kr = t >> 5;               // row, step 8
            #pragma unroll
            for (int r = 0; r < KT; r += 8) {
                float4 v = *(const float4*)(W + (size_t)(k0 + kr + r) * 128 + lr * 4);
                *(float4*)&Ws[kr + r][lr * 4] = v;
            }
        }
        // stage A tile: NT x KT (64 rows x 8 float4 = 512 float4, 2/thread)
        {
            constexpr int F4 = KT / 4;     // 8 float4 per row
            int g = t % F4;
            int r = t / F4;                // 32 rows per pass
            #pragma unroll
            for (int rr = 0; rr < NT; rr += 256 / F4) {
                int row = r + rr;
                int n = n0 + row;
                int nc = n < N ? n : N - 1;   // clamp; stores guarded later
                float4 v = *(const float4*)(A + (size_t)nc * K + k0 + g * 4);
                if (HAS_ADD) {
                    float4 u = *(const float4*)(Aadd + (size_t)nc * K + k0 + g * 4);
                    v.x += u.x; v.y += u.y; v.z += u.z; v.w += u.w;
                }
                *(float4*)&As[row][g * 4] = v;
            }
        }
        __syncthreads();
        #pragma unroll
        for (int k = 0; k < KT; k += 4) {
            float4 w0 = *(const float4*)&Ws[k + 0][tx * 4];
            float4 w1 = *(const float4*)&Ws[k + 1][tx * 4];
            float4 w2 = *(const float4*)&Ws[k + 2][tx * 4];
            float4 w3 = *(const float4*)&Ws[k + 3][tx * 4];
            #pragma unroll
            for (int i = 0; i < 8; i++) {
                float4 a = *(const float4*)&As[ty * 8 + i][k];
                acc[i][0] += a.x * w0.x + a.y * w1.x + a.z * w2.x + a.w * w3.x;
                acc[i][1] += a.x * w0.y + a.y * w1.y + a.z * w2.y + a.w * w3.y;
                acc[i][2] += a.x * w0.z + a.y * w1.z + a.z * w2.z + a.w * w3.z;
                acc[i][3] += a.x * w0.w + a.y * w1.w + a.z * w2.w + a.w * w3.w;
            }
        }
        __syncthreads();
    }
    float4 b = *(const float4*)(bias + tx * 4);
    #pragma unroll
    for (int i = 0; i < 8; i++) {
        int n = n0 + ty * 8 + i;
        if (n < N) {
            float4 o;
            o.x = acc[i][0] + b.x; o.y = acc[i][1] + b.y;
            o.z = acc[i][2] + b.z; o.w = acc[i][3] + b.w;
            if (RELU) {
                o.x = fmaxf(o.x, 0.f); o.y = fmaxf(o.y, 0.f);
                o.z = fmaxf(o.z, 0.f); o.w = fmaxf(o.w, 0.f);
            }
            *(float4*)(out + (size_t)n * 128 + tx * 4) = o;
        }
    }
}

// ---------------- output head ----------------
__global__ __launch_bounds__(256) void out_dot_kernel(
    const float* __restrict__ h2, const float* __restrict__ Wout,
    const float* __restrict__ bout, float* __restrict__ out, int N)
{
    int gt = blockIdx.x * blockDim.x + threadIdx.x;
    int wave = gt >> 6;
    int lane = threadIdx.x & 63;
    if (wave >= N) return;
    const float* row = h2 + (size_t)wave * 128;
    float p = row[lane] * Wout[lane] + row[lane + 64] * Wout[lane + 64];
    #pragma unroll
    for (int off = 32; off; off >>= 1) p += __shfl_down(p, off);
    if (lane == 0) out[wave] = p + bout[0];
}

extern "C" void kernel_launch(void* const* d_in, const int* in_sizes, int n_in,
                              void* d_out, int out_size, void* d_ws, size_t ws_size,
                              hipStream_t stream) {
    const float* x    = (const float*)d_in[0];
    const void*  ei   = d_in[1];
    const float* W1   = (const float*)d_in[2];
    const float* b1   = (const float*)d_in[3];
    const float* W2   = (const float*)d_in[4];
    const float* b2   = (const float*)d_in[5];
    const float* W3   = (const float*)d_in[6];
    const float* b3   = (const float*)d_in[7];
    const float* W4   = (const float*)d_in[8];
    const float* b4   = (const float*)d_in[9];
    const float* Wout = (const float*)d_in[10];
    const float* bout = (const float*)d_in[11];
    float* out = (float*)d_out;

    const int E = in_sizes[1] / 2;
    const int N = N_NODES;
    const int nb = (N + 255) / 256;   // 196 scan blocks

    char* wsb = (char*)d_ws;
    int*   flag   = (int*)wsb;                         // 256 B
    int*   deg    = (int*)(wsb + 256);                 // N ints (reused as cursor)
    int*   rowptr = deg + N;                           // N+1 ints
    int*   bsum   = rowptr + N + 1;                    // 256 ints
    int*   bsx    = bsum + 256;                        // 256 ints
    int*   col    = bsx + 256;                         // E ints
    float* bufA   = (float*)(col + E);                 // N*128 (agg)
    float* bufB   = bufA + (size_t)N * HID;
    float* bufC   = bufB + (size_t)N * HID;

    detect64_kernel<<<1, 256, 0, stream>>>((const int*)ei, flag);

    // ---- build CSR (once, reused by both layers) ----
    hipMemsetAsync(deg, 0, (size_t)N * sizeof(int), stream);
    hist_kernel<<<(E + 255) / 256, 256, 0, stream>>>(ei, flag, deg, E);
    scan1_kernel<<<nb, 256, 0, stream>>>(deg, rowptr, bsum, N);
    scan2_kernel<<<1, 256, 0, stream>>>(bsum, bsx, nb);
    scan3_kernel<<<nb, 256, 0, stream>>>(deg, rowptr, bsx, N);  // deg becomes cursor
    fill_kernel<<<(E + 255) / 256, 256, 0, stream>>>(ei, flag, deg, col, E);

    const int agg_blocks = (N * 64 + 255) / 256;   // wave per node, 4 waves/block
    const int gemm_blocks = (N + 63) / 64;

    // ---- layer 1 ----
    gather_agg_kernel<IN_CH><<<agg_blocks, 256, 0, stream>>>(x, rowptr, col, bufA, N);
    gemm_mlp_kernel<IN_CH, true, true><<<gemm_blocks, 256, 0, stream>>>(
        x, bufA, W1, b1, bufB, N);                     // t1
    gemm_mlp_kernel<HID, true, false><<<gemm_blocks, 256, 0, stream>>>(
        bufB, nullptr, W2, b2, bufC, N);               // h1

    // ---- layer 2 ----
    gather_agg_kernel<HID><<<agg_blocks, 256, 0, stream>>>(bufC, rowptr, col, bufA, N);
    gemm_mlp_kernel<HID, true, true><<<gemm_blocks, 256, 0, stream>>>(
        bufC, bufA, W3, b3, bufB, N);                  // t2
    gemm_mlp_kernel<HID, true, false><<<gemm_blocks, 256, 0, stream>>>(
        bufB, nullptr, W4, b4, bufC, N);               // h2

    // ---- output head ----
    out_dot_kernel<<<(N * 64 + 255) / 256, 256, 0, stream>>>(
        bufC, Wout, bout, out, N);
}

// Round 4
// 443.530 us; speedup vs baseline: 3.1669x; 3.1669x over previous
//
#include <hip/hip_runtime.h>

// GIN: 2x GINConv(eps=0, MLP 2-layer) + ReLU, then Linear(128->1).
// N=50000 nodes, E=800000 edges, IN=64, HID=128.
//
// Round 4: fix GEMM spills properly. Round 2 (VGPR=256 + spill) and round 3
// (launch_bounds cap -> VGPR=64, acc spilled, 1GB scratch traffic) both lost
// to the register allocator. Fix = reduce demand: #pragma unroll 2 on the
// inner k-loop (not full unroll), no min-waves launch_bounds cap.

#define N_NODES 50000
#define IN_CH 64
#define HID 128

// ---------------- edge dtype detection (int64 vs int32) ----------------
__global__ void detect64_kernel(const int* __restrict__ ei32, int* __restrict__ flag) {
    int t = threadIdx.x;  // 256 threads
    int v = ei32[2 * t + 1];
    unsigned long long b = __ballot(v != 0);
    __shared__ unsigned long long r[4];
    if ((t & 63) == 0) r[t >> 6] = b;
    __syncthreads();
    if (t == 0) flag[0] = ((r[0] | r[1] | r[2] | r[3]) == 0ULL) ? 1 : 0;
}

__device__ __forceinline__ int load_idx(const void* ei, int is64, int pos) {
    if (is64) return (int)((const long long*)ei)[pos];
    return ((const int*)ei)[pos];
}

// ---------------- CSR build ----------------
__global__ __launch_bounds__(256) void hist_kernel(
    const void* __restrict__ ei, const int* __restrict__ is64,
    int* __restrict__ deg, int E)
{
    int e = blockIdx.x * blockDim.x + threadIdx.x;
    if (e >= E) return;
    int d = load_idx(ei, *is64, E + e);
    atomicAdd(&deg[d], 1);
}

__device__ __forceinline__ int wave_incl_scan(int v, int lane) {
    #pragma unroll
    for (int off = 1; off < 64; off <<= 1) {
        int u = __shfl_up(v, off);
        if (lane >= off) v += u;
    }
    return v;
}

__global__ __launch_bounds__(256) void scan1_kernel(
    const int* __restrict__ deg, int* __restrict__ incl,
    int* __restrict__ bsum, int N)
{
    int i = blockIdx.x * 256 + threadIdx.x;
    int lane = threadIdx.x & 63;
    int w = threadIdx.x >> 6;
    int v = (i < N) ? deg[i] : 0;
    int s = wave_incl_scan(v, lane);
    __shared__ int wsum[4];
    if (lane == 63) wsum[w] = s;
    __syncthreads();
    int off = 0;
    #pragma unroll
    for (int k = 0; k < 4; k++) if (k < w) off += wsum[k];
    s += off;
    if (i < N) incl[i] = s;
    if (threadIdx.x == 255) bsum[blockIdx.x] = s;
}

__global__ __launch_bounds__(256) void scan2_kernel(
    const int* __restrict__ bsum, int* __restrict__ bsx, int nb)
{
    int t = threadIdx.x;
    int lane = t & 63;
    int w = t >> 6;
    int v = (t < nb) ? bsum[t] : 0;
    int s = wave_incl_scan(v, lane);
    __shared__ int wsum[4];
    if (lane == 63) wsum[w] = s;
    __syncthreads();
    int off = 0;
    #pragma unroll
    for (int k = 0; k < 4; k++) if (k < w) off += wsum[k];
    s += off;
    if (t < nb) bsx[t] = s - v;   // exclusive
}

__global__ __launch_bounds__(256) void scan3_kernel(
    int* __restrict__ deg_cursor, int* __restrict__ incl_rowptr,
    const int* __restrict__ bsx, int N)
{
    int i = blockIdx.x * 256 + threadIdx.x;
    if (i >= N) return;
    int incl = incl_rowptr[i] + bsx[blockIdx.x];
    int d = deg_cursor[i];
    int excl = incl - d;
    incl_rowptr[i] = excl;        // row_ptr[i]
    deg_cursor[i] = excl;         // cursor[i]
    if (i == N - 1) incl_rowptr[N] = incl;
}

__global__ __launch_bounds__(256) void fill_kernel(
    const void* __restrict__ ei, const int* __restrict__ is64,
    int* __restrict__ cursor, int* __restrict__ col, int E)
{
    int e = blockIdx.x * blockDim.x + threadIdx.x;
    if (e >= E) return;
    int i64 = *is64;
    int s = load_idx(ei, i64, e);
    int d = load_idx(ei, i64, E + e);
    int pos = atomicAdd(&cursor[d], 1);
    col[pos] = s;
}

// ---------------- gather aggregation: agg[n] = sum_{j in nbrs(n)} h[j] ----------------
template<int C>
__global__ __launch_bounds__(256) void gather_agg_kernel(
    const float* __restrict__ h, const int* __restrict__ rp,
    const int* __restrict__ col, float* __restrict__ agg, int N)
{
    int wid = (blockIdx.x * blockDim.x + threadIdx.x) >> 6;
    int lane = threadIdx.x & 63;
    if (wid >= N) return;
    int b = rp[wid], e2 = rp[wid + 1];
    float2 acc = make_float2(0.f, 0.f);
    for (int base = b; base < e2; base += 64) {
        int cnt = e2 - base; if (cnt > 64) cnt = 64;
        int myc = (base + lane < e2) ? col[base + lane] : 0;
        for (int j = 0; j < cnt; j++) {
            int s = __shfl(myc, j);
            if (C == 128) {
                float2 v = *(const float2*)(h + (size_t)s * C + lane * 2);
                acc.x += v.x; acc.y += v.y;
            } else {
                acc.x += h[(size_t)s * C + lane];
            }
        }
    }
    if (C == 128) {
        *(float2*)(agg + (size_t)wid * C + lane * 2) = acc;
    } else {
        agg[(size_t)wid * C + lane] = acc.x;
    }
}

// ---------------- fp32 GEMM: out[N][128] = act((A (+Aadd)) @ W + b) ----------------
// 64 rows/block, 256 threads, 8x4 register tile. KT=32.
// LDS: Ws 32x128 (16KB) + As 64x36 (9.2KB) = ~25KB.
// Inner k-loop unroll 2 keeps live set ~100 VGPR -> no spills.
template<int K, bool RELU, bool HAS_ADD>
__global__ __launch_bounds__(256) void gemm_mlp_kernel(
    const float* __restrict__ A, const float* __restrict__ Aadd,
    const float* __restrict__ W, const float* __restrict__ bias,
    float* __restrict__ out, int N)
{
    constexpr int KT = 32;
    constexpr int NT = 64;
    __shared__ float Ws[KT][128];
    __shared__ float As[NT][KT + 4];

    const int t  = threadIdx.x;
    const int tx = t & 31;                 // col group: cols tx*4 .. tx*4+3
    const int ty = t >> 5;                 // row group: rows ty*8 .. ty*8+7
    const int n0 = blockIdx.x * NT;

    float acc[8][4];
    #pragma unroll
    for (int i = 0; i < 8; i++)
        #pragma unroll
        for (int j = 0; j < 4; j++) acc[i][j] = 0.f;

    #pragma unroll 1
    for (int k0 = 0; k0 < K; k0 += KT) {
        // stage W tile: KT x 128 (32 rows x 32 float4, 4 per thread)
        {
            int lr = t & 31;               // float4 index in row
            int kr = t >> 5;               // row, step 8
            #pragma unroll
            for (int r = 0; r < KT; r += 8) {
                float4 v = *(const float4*)(W + (size_t)(k0 + kr + r) * 128 + lr * 4);
                *(float4*)&Ws[kr + r][lr * 4] = v;
            }
        }
        // stage A tile: NT x KT (64 rows x 8 float4, 2 per thread)
        {
            constexpr int F4 = KT / 4;     // 8 float4 per row
            int g = t % F4;
            int r = t / F4;                // 32 rows per pass
            #pragma unroll
            for (int rr = 0; rr < NT; rr += 256 / F4) {
                int row = r + rr;
                int n = n0 + row;
                int nc = n < N ? n : N - 1;   // clamp; stores guarded later
                float4 v = *(const float4*)(A + (size_t)nc * K + k0 + g * 4);
                if (HAS_ADD) {
                    float4 u = *(const float4*)(Aadd + (size_t)nc * K + k0 + g * 4);
                    v.x += u.x; v.y += u.y; v.z += u.z; v.w += u.w;
                }
                *(float4*)&As[row][g * 4] = v;
            }
        }
        __syncthreads();
        #pragma unroll 2
        for (int k = 0; k < KT; k += 4) {
            float4 w0 = *(const float4*)&Ws[k + 0][tx * 4];
            float4 w1 = *(const float4*)&Ws[k + 1][tx * 4];
            float4 w2 = *(const float4*)&Ws[k + 2][tx * 4];
            float4 w3 = *(const float4*)&Ws[k + 3][tx * 4];
            #pragma unroll
            for (int i = 0; i < 8; i++) {
                float4 a = *(const float4*)&As[ty * 8 + i][k];
                acc[i][0] += a.x * w0.x + a.y * w1.x + a.z * w2.x + a.w * w3.x;
                acc[i][1] += a.x * w0.y + a.y * w1.y + a.z * w2.y + a.w * w3.y;
                acc[i][2] += a.x * w0.z + a.y * w1.z + a.z * w2.z + a.w * w3.z;
                acc[i][3] += a.x * w0.w + a.y * w1.w + a.z * w2.w + a.w * w3.w;
            }
        }
        __syncthreads();
    }
    float4 b = *(const float4*)(bias + tx * 4);
    #pragma unroll
    for (int i = 0; i < 8; i++) {
        int n = n0 + ty * 8 + i;
        if (n < N) {
            float4 o;
            o.x = acc[i][0] + b.x; o.y = acc[i][1] + b.y;
            o.z = acc[i][2] + b.z; o.w = acc[i][3] + b.w;
            if (RELU) {
                o.x = fmaxf(o.x, 0.f); o.y = fmaxf(o.y, 0.f);
                o.z = fmaxf(o.z, 0.f); o.w = fmaxf(o.w, 0.f);
            }
            *(float4*)(out + (size_t)n * 128 + tx * 4) = o;
        }
    }
}

// ---------------- output head ----------------
__global__ __launch_bounds__(256) void out_dot_kernel(
    const float* __restrict__ h2, const float* __restrict__ Wout,
    const float* __restrict__ bout, float* __restrict__ out, int N)
{
    int gt = blockIdx.x * blockDim.x + threadIdx.x;
    int wave = gt >> 6;
    int lane = threadIdx.x & 63;
    if (wave >= N) return;
    const float* row = h2 + (size_t)wave * 128;
    float p = row[lane] * Wout[lane] + row[lane + 64] * Wout[lane + 64];
    #pragma unroll
    for (int off = 32; off; off >>= 1) p += __shfl_down(p, off);
    if (lane == 0) out[wave] = p + bout[0];
}

extern "C" void kernel_launch(void* const* d_in, const int* in_sizes, int n_in,
                              void* d_out, int out_size, void* d_ws, size_t ws_size,
                              hipStream_t stream) {
    const float* x    = (const float*)d_in[0];
    const void*  ei   = d_in[1];
    const float* W1   = (const float*)d_in[2];
    const float* b1   = (const float*)d_in[3];
    const float* W2   = (const float*)d_in[4];
    const float* b2   = (const float*)d_in[5];
    const float* W3   = (const float*)d_in[6];
    const float* b3   = (const float*)d_in[7];
    const float* W4   = (const float*)d_in[8];
    const float* b4   = (const float*)d_in[9];
    const float* Wout = (const float*)d_in[10];
    const float* bout = (const float*)d_in[11];
    float* out = (float*)d_out;

    const int E = in_sizes[1] / 2;
    const int N = N_NODES;
    const int nb = (N + 255) / 256;   // 196 scan blocks

    char* wsb = (char*)d_ws;
    int*   flag   = (int*)wsb;                         // 256 B
    int*   deg    = (int*)(wsb + 256);                 // N ints (reused as cursor)
    int*   rowptr = deg + N;                           // N+1 ints
    int*   bsum   = rowptr + N + 1;                    // 256 ints
    int*   bsx    = bsum + 256;                        // 256 ints
    int*   col    = bsx + 256;                         // E ints
    float* bufA   = (float*)(col + E);                 // N*128 (agg)
    float* bufB   = bufA + (size_t)N * HID;
    float* bufC   = bufB + (size_t)N * HID;

    detect64_kernel<<<1, 256, 0, stream>>>((const int*)ei, flag);

    // ---- build CSR (once, reused by both layers) ----
    hipMemsetAsync(deg, 0, (size_t)N * sizeof(int), stream);
    hist_kernel<<<(E + 255) / 256, 256, 0, stream>>>(ei, flag, deg, E);
    scan1_kernel<<<nb, 256, 0, stream>>>(deg, rowptr, bsum, N);
    scan2_kernel<<<1, 256, 0, stream>>>(bsum, bsx, nb);
    scan3_kernel<<<nb, 256, 0, stream>>>(deg, rowptr, bsx, N);  // deg becomes cursor
    fill_kernel<<<(E + 255) / 256, 256, 0, stream>>>(ei, flag, deg, col, E);

    const int agg_blocks = (N * 64 + 255) / 256;   // wave per node, 4 waves/block
    const int gemm_blocks = (N + 63) / 64;

    // ---- layer 1 ----
    gather_agg_kernel<IN_CH><<<agg_blocks, 256, 0, stream>>>(x, rowptr, col, bufA, N);
    gemm_mlp_kernel<IN_CH, true, true><<<gemm_blocks, 256, 0, stream>>>(
        x, bufA, W1, b1, bufB, N);                     // t1
    gemm_mlp_kernel<HID, true, false><<<gemm_blocks, 256, 0, stream>>>(
        bufB, nullptr, W2, b2, bufC, N);               // h1

    // ---- layer 2 ----
    gather_agg_kernel<HID><<<agg_blocks, 256, 0, stream>>>(bufC, rowptr, col, bufA, N);
    gemm_mlp_kernel<HID, true, true><<<gemm_blocks, 256, 0, stream>>>(
        bufC, bufA, W3, b3, bufB, N);                  // t2
    gemm_mlp_kernel<HID, true, false><<<gemm_blocks, 256, 0, stream>>>(
        bufB, nullptr, W4, b4, bufC, N);               // h2

    // ---- output head ----
    out_dot_kernel<<<(N * 64 + 255) / 256, 256, 0, stream>>>(
        bufC, Wout, bout, out, N);
}

// Round 5
// 371.432 us; speedup vs baseline: 3.7816x; 1.1941x over previous
//
#include <hip/hip_runtime.h>

// GIN: 2x GINConv(eps=0, MLP 2-layer) + ReLU, then Linear(128->1).
// N=50000 nodes, E=800000 edges, IN=64, HID=128.
//
// Round 5: GEMMs via MFMA with split-bf16 (hi/lo) fp32 emulation:
// out = Ah*Wh + Al*Wh + Ah*Wl  (3 MFMA passes, ~2^-17 rel precision).
// W pre-split+transposed once per launch; A split during LDS staging.
// Gather now fuses the +self term, so every GEMM is single-input.

#define N_NODES 50000
#define IN_CH 64
#define HID 128

typedef short short8 __attribute__((ext_vector_type(8)));
typedef float f32x4 __attribute__((ext_vector_type(4)));

__device__ __forceinline__ unsigned bf16_rne(float f) {
    unsigned u = __float_as_uint(f);
    return (u + 0x7FFFu + ((u >> 16) & 1u)) >> 16;
}

// ---------------- edge dtype detection (int64 vs int32) ----------------
__global__ void detect64_kernel(const int* __restrict__ ei32, int* __restrict__ flag) {
    int t = threadIdx.x;  // 256 threads
    int v = ei32[2 * t + 1];
    unsigned long long b = __ballot(v != 0);
    __shared__ unsigned long long r[4];
    if ((t & 63) == 0) r[t >> 6] = b;
    __syncthreads();
    if (t == 0) flag[0] = ((r[0] | r[1] | r[2] | r[3]) == 0ULL) ? 1 : 0;
}

__device__ __forceinline__ int load_idx(const void* ei, int is64, int pos) {
    if (is64) return (int)((const long long*)ei)[pos];
    return ((const int*)ei)[pos];
}

// ---------------- CSR build ----------------
__global__ __launch_bounds__(256) void hist_kernel(
    const void* __restrict__ ei, const int* __restrict__ is64,
    int* __restrict__ deg, int E)
{
    int e = blockIdx.x * blockDim.x + threadIdx.x;
    if (e >= E) return;
    int d = load_idx(ei, *is64, E + e);
    atomicAdd(&deg[d], 1);
}

__device__ __forceinline__ int wave_incl_scan(int v, int lane) {
    #pragma unroll
    for (int off = 1; off < 64; off <<= 1) {
        int u = __shfl_up(v, off);
        if (lane >= off) v += u;
    }
    return v;
}

__global__ __launch_bounds__(256) void scan1_kernel(
    const int* __restrict__ deg, int* __restrict__ incl,
    int* __restrict__ bsum, int N)
{
    int i = blockIdx.x * 256 + threadIdx.x;
    int lane = threadIdx.x & 63;
    int w = threadIdx.x >> 6;
    int v = (i < N) ? deg[i] : 0;
    int s = wave_incl_scan(v, lane);
    __shared__ int wsum[4];
    if (lane == 63) wsum[w] = s;
    __syncthreads();
    int off = 0;
    #pragma unroll
    for (int k = 0; k < 4; k++) if (k < w) off += wsum[k];
    s += off;
    if (i < N) incl[i] = s;
    if (threadIdx.x == 255) bsum[blockIdx.x] = s;
}

__global__ __launch_bounds__(256) void scan2_kernel(
    const int* __restrict__ bsum, int* __restrict__ bsx, int nb)
{
    int t = threadIdx.x;
    int lane = t & 63;
    int w = t >> 6;
    int v = (t < nb) ? bsum[t] : 0;
    int s = wave_incl_scan(v, lane);
    __shared__ int wsum[4];
    if (lane == 63) wsum[w] = s;
    __syncthreads();
    int off = 0;
    #pragma unroll
    for (int k = 0; k < 4; k++) if (k < w) off += wsum[k];
    s += off;
    if (t < nb) bsx[t] = s - v;   // exclusive
}

__global__ __launch_bounds__(256) void scan3_kernel(
    int* __restrict__ deg_cursor, int* __restrict__ incl_rowptr,
    const int* __restrict__ bsx, int N)
{
    int i = blockIdx.x * 256 + threadIdx.x;
    if (i >= N) return;
    int incl = incl_rowptr[i] + bsx[blockIdx.x];
    int d = deg_cursor[i];
    int excl = incl - d;
    incl_rowptr[i] = excl;        // row_ptr[i]
    deg_cursor[i] = excl;         // cursor[i]
    if (i == N - 1) incl_rowptr[N] = incl;
}

__global__ __launch_bounds__(256) void fill_kernel(
    const void* __restrict__ ei, const int* __restrict__ is64,
    int* __restrict__ cursor, int* __restrict__ col, int E)
{
    int e = blockIdx.x * blockDim.x + threadIdx.x;
    if (e >= E) return;
    int i64 = *is64;
    int s = load_idx(ei, i64, e);
    int d = load_idx(ei, i64, E + e);
    int pos = atomicAdd(&cursor[d], 1);
    col[pos] = s;
}

// ---------------- W split: W fp32 [K][128] -> Wh/Wl bf16 [128][K] (transposed) ----------------
template<int K>
__global__ __launch_bounds__(256) void wsplit_kernel(
    const float* __restrict__ W, ushort* __restrict__ Wh, ushort* __restrict__ Wl)
{
    int i = blockIdx.x * 256 + threadIdx.x;
    if (i >= 128 * K) return;
    int n = i / K, k = i % K;              // K is a power of 2 -> shifts
    float w = W[(size_t)k * 128 + n];
    unsigned h = bf16_rne(w);
    float hf = __uint_as_float(h << 16);
    unsigned lo = bf16_rne(w - hf);
    Wh[(size_t)n * K + k] = (ushort)h;
    Wl[(size_t)n * K + k] = (ushort)lo;
}

// ---------------- gather aggregation: out[n] = h[n] + sum_{j in nbrs(n)} h[j] ----------------
template<int C>
__global__ __launch_bounds__(256) void gather_agg_kernel(
    const float* __restrict__ h, const int* __restrict__ rp,
    const int* __restrict__ col, float* __restrict__ out, int N)
{
    int wid = (blockIdx.x * blockDim.x + threadIdx.x) >> 6;
    int lane = threadIdx.x & 63;
    if (wid >= N) return;
    int b = rp[wid], e2 = rp[wid + 1];
    float2 acc = make_float2(0.f, 0.f);
    for (int base = b; base < e2; base += 64) {
        int cnt = e2 - base; if (cnt > 64) cnt = 64;
        int myc = (base + lane < e2) ? col[base + lane] : 0;
        for (int j = 0; j < cnt; j++) {
            int s = __shfl(myc, j);
            if (C == 128) {
                float2 v = *(const float2*)(h + (size_t)s * C + lane * 2);
                acc.x += v.x; acc.y += v.y;
            } else {
                acc.x += h[(size_t)s * C + lane];
            }
        }
    }
    // fused self term (GIN eps=0: x_i + sum_j x_j)
    if (C == 128) {
        float2 v = *(const float2*)(h + (size_t)wid * C + lane * 2);
        acc.x += v.x; acc.y += v.y;
        *(float2*)(out + (size_t)wid * C + lane * 2) = acc;
    } else {
        acc.x += h[(size_t)wid * C + lane];
        out[(size_t)wid * C + lane] = acc.x;
    }
}

// ---------------- MFMA GEMM: out[N][128] = relu(A @ W + b), split-bf16 fp32 emu ----------------
// A fp32 [N][K]; Whg/Wlg bf16 [128][K] (transposed, pre-split).
// Block: 64 rows x 128 cols, 256 threads (4 waves, 16 rows each).
// Per k-step (32): stage A (split hi/lo) + W tiles into LDS, then per wave
// 8 col-tiles x 3 MFMA (16x16x32 bf16).
template<int K>
__global__ __launch_bounds__(256) void gemm_mfma_kernel(
    const float* __restrict__ A, const ushort* __restrict__ Whg,
    const ushort* __restrict__ Wlg, const float* __restrict__ bias,
    float* __restrict__ out, int N)
{
    __shared__ ushort Ah[64][40], Al[64][40];      // pad to 40 (80B stride)
    __shared__ ushort Wh[128][40], Wl[128][40];    // total 30720 B

    const int t  = threadIdx.x;
    const int n0 = blockIdx.x * 64;
    const int w  = t >> 6, l = t & 63;
    const int lr = l & 15, lg = l >> 4;

    f32x4 acc[8];
    #pragma unroll
    for (int c = 0; c < 8; c++) acc[c] = (f32x4){0.f, 0.f, 0.f, 0.f};

    #pragma unroll 1
    for (int k0 = 0; k0 < K; k0 += 32) {
        // ---- stage A tile 64x32, split into hi/lo bf16 ----
        {
            int row = t >> 2, seg = t & 3;
            int n = n0 + row; int nc = n < N ? n : N - 1;
            const float* p = A + (size_t)nc * K + k0 + seg * 8;
            float4 f0 = *(const float4*)p;
            float4 f1 = *(const float4*)(p + 4);
            float fs[8] = {f0.x, f0.y, f0.z, f0.w, f1.x, f1.y, f1.z, f1.w};
            unsigned hh[8], ll[8];
            #pragma unroll
            for (int j = 0; j < 8; j++) {
                hh[j] = bf16_rne(fs[j]);
                float hf = __uint_as_float(hh[j] << 16);
                ll[j] = bf16_rne(fs[j] - hf);
            }
            uint4 hv = make_uint4(hh[0] | (hh[1] << 16), hh[2] | (hh[3] << 16),
                                  hh[4] | (hh[5] << 16), hh[6] | (hh[7] << 16));
            uint4 lv = make_uint4(ll[0] | (ll[1] << 16), ll[2] | (ll[3] << 16),
                                  ll[4] | (ll[5] << 16), ll[6] | (ll[7] << 16));
            *(uint4*)&Ah[row][seg * 8] = hv;
            *(uint4*)&Al[row][seg * 8] = lv;
        }
        // ---- stage W tiles 128x32 (hi and lo) ----
        {
            int n = t >> 1, half = t & 1;
            const uint4* ph = (const uint4*)(Whg + (size_t)n * K + k0 + half * 16);
            const uint4* pl = (const uint4*)(Wlg + (size_t)n * K + k0 + half * 16);
            uint4 a0 = ph[0], a1 = ph[1];
            uint4 b0 = pl[0], b1 = pl[1];
            uint4* dh = (uint4*)&Wh[n][half * 16];
            uint4* dl = (uint4*)&Wl[n][half * 16];
            dh[0] = a0; dh[1] = a1;
            dl[0] = b0; dl[1] = b1;
        }
        __syncthreads();
        short8 ah = *(const short8*)&Ah[w * 16 + lr][lg * 8];
        short8 al = *(const short8*)&Al[w * 16 + lr][lg * 8];
        #pragma unroll
        for (int c = 0; c < 8; c++) {
            short8 bh = *(const short8*)&Wh[c * 16 + lr][lg * 8];
            short8 bl = *(const short8*)&Wl[c * 16 + lr][lg * 8];
            acc[c] = __builtin_amdgcn_mfma_f32_16x16x32_bf16(ah, bh, acc[c], 0, 0, 0);
            acc[c] = __builtin_amdgcn_mfma_f32_16x16x32_bf16(al, bh, acc[c], 0, 0, 0);
            acc[c] = __builtin_amdgcn_mfma_f32_16x16x32_bf16(ah, bl, acc[c], 0, 0, 0);
        }
        __syncthreads();
    }
    // ---- epilogue: D tile-local col = lr, row = lg*4 + j ----
    #pragma unroll
    for (int c = 0; c < 8; c++) {
        float bc = bias[c * 16 + lr];
        #pragma unroll
        for (int j = 0; j < 4; j++) {
            int row = n0 + w * 16 + lg * 4 + j;
            if (row < N) {
                float v = acc[c][j] + bc;
                out[(size_t)row * 128 + c * 16 + lr] = fmaxf(v, 0.f);
            }
        }
    }
}

// ---------------- output head ----------------
__global__ __launch_bounds__(256) void out_dot_kernel(
    const float* __restrict__ h2, const float* __restrict__ Wout,
    const float* __restrict__ bout, float* __restrict__ out, int N)
{
    int gt = blockIdx.x * blockDim.x + threadIdx.x;
    int wave = gt >> 6;
    int lane = threadIdx.x & 63;
    if (wave >= N) return;
    const float* row = h2 + (size_t)wave * 128;
    float p = row[lane] * Wout[lane] + row[lane + 64] * Wout[lane + 64];
    #pragma unroll
    for (int off = 32; off; off >>= 1) p += __shfl_down(p, off);
    if (lane == 0) out[wave] = p + bout[0];
}

extern "C" void kernel_launch(void* const* d_in, const int* in_sizes, int n_in,
                              void* d_out, int out_size, void* d_ws, size_t ws_size,
                              hipStream_t stream) {
    const float* x    = (const float*)d_in[0];
    const void*  ei   = d_in[1];
    const float* W1   = (const float*)d_in[2];
    const float* b1   = (const float*)d_in[3];
    const float* W2   = (const float*)d_in[4];
    const float* b2   = (const float*)d_in[5];
    const float* W3   = (const float*)d_in[6];
    const float* b3   = (const float*)d_in[7];
    const float* W4   = (const float*)d_in[8];
    const float* b4   = (const float*)d_in[9];
    const float* Wout = (const float*)d_in[10];
    const float* bout = (const float*)d_in[11];
    float* out = (float*)d_out;

    const int E = in_sizes[1] / 2;
    const int N = N_NODES;
    const int nb = (N + 255) / 256;   // 196 scan blocks

    // ---- workspace layout (256B-aligned slots) ----
    char* wsb = (char*)d_ws;
    size_t off = 0;
    auto alloc = [&](size_t bytes) -> void* {
        void* p = wsb + off;
        off = (off + bytes + 255) & ~(size_t)255;
        return p;
    };
    int*    flag   = (int*)alloc(4);
    int*    deg    = (int*)alloc((size_t)N * 4);          // reused as cursor
    int*    rowptr = (int*)alloc((size_t)(N + 1) * 4);
    int*    bsum   = (int*)alloc(256 * 4);
    int*    bsx    = (int*)alloc(256 * 4);
    int*    col    = (int*)alloc((size_t)E * 4);
    ushort* w1h    = (ushort*)alloc(128 * 64 * 2);
    ushort* w1l    = (ushort*)alloc(128 * 64 * 2);
    ushort* w2h    = (ushort*)alloc(128 * 128 * 2);
    ushort* w2l    = (ushort*)alloc(128 * 128 * 2);
    ushort* w3h    = (ushort*)alloc(128 * 128 * 2);
    ushort* w3l    = (ushort*)alloc(128 * 128 * 2);
    ushort* w4h    = (ushort*)alloc(128 * 128 * 2);
    ushort* w4l    = (ushort*)alloc(128 * 128 * 2);
    float*  bufA   = (float*)alloc((size_t)N * HID * 4);  // agg/sum buffer
    float*  bufB   = (float*)alloc((size_t)N * HID * 4);
    float*  bufC   = (float*)alloc((size_t)N * HID * 4);

    detect64_kernel<<<1, 256, 0, stream>>>((const int*)ei, flag);

    // ---- build CSR (once, reused by both layers) ----
    hipMemsetAsync(deg, 0, (size_t)N * sizeof(int), stream);
    hist_kernel<<<(E + 255) / 256, 256, 0, stream>>>(ei, flag, deg, E);
    scan1_kernel<<<nb, 256, 0, stream>>>(deg, rowptr, bsum, N);
    scan2_kernel<<<1, 256, 0, stream>>>(bsum, bsx, nb);
    scan3_kernel<<<nb, 256, 0, stream>>>(deg, rowptr, bsx, N);  // deg becomes cursor
    fill_kernel<<<(E + 255) / 256, 256, 0, stream>>>(ei, flag, deg, col, E);

    // ---- pre-split weights to bf16 hi/lo (transposed) ----
    wsplit_kernel<64> <<<(128 * 64 + 255) / 256, 256, 0, stream>>>(W1, w1h, w1l);
    wsplit_kernel<128><<<(128 * 128 + 255) / 256, 256, 0, stream>>>(W2, w2h, w2l);
    wsplit_kernel<128><<<(128 * 128 + 255) / 256, 256, 0, stream>>>(W3, w3h, w3l);
    wsplit_kernel<128><<<(128 * 128 + 255) / 256, 256, 0, stream>>>(W4, w4h, w4l);

    const int agg_blocks  = (N * 64 + 255) / 256;   // wave per node
    const int gemm_blocks = (N + 63) / 64;          // 782

    // ---- layer 1 ----
    gather_agg_kernel<IN_CH><<<agg_blocks, 256, 0, stream>>>(x, rowptr, col, bufA, N);
    gemm_mfma_kernel<IN_CH><<<gemm_blocks, 256, 0, stream>>>(
        bufA, w1h, w1l, b1, bufB, N);                  // t1 = relu((x+agg)@W1+b1)
    gemm_mfma_kernel<HID><<<gemm_blocks, 256, 0, stream>>>(
        bufB, w2h, w2l, b2, bufC, N);                  // h1 = relu(t1@W2+b2)

    // ---- layer 2 ----
    gather_agg_kernel<HID><<<agg_blocks, 256, 0, stream>>>(bufC, rowptr, col, bufA, N);
    gemm_mfma_kernel<HID><<<gemm_blocks, 256, 0, stream>>>(
        bufA, w3h, w3l, b3, bufB, N);                  // t2
    gemm_mfma_kernel<HID><<<gemm_blocks, 256, 0, stream>>>(
        bufB, w4h, w4l, b4, bufC, N);                  // h2

    // ---- output head ----
    out_dot_kernel<<<(N * 64 + 255) / 256, 256, 0, stream>>>(
        bufC, Wout, bout, out, N);
}